// Round 8
// baseline (916.000 us; speedup 1.0000x reference)
//
#include <hip/hip_runtime.h>
#include <math.h>

#define NB    8192
#define EMB   512
#define POOL  100

// fused-kernel geometry: 512 blocks x 256 threads, 16 rows/block, 2 blocks/CU
#define BM    16
#define BN    256     // j-tile (2 jt passes)
#define BK    32      // k-chunk
#define AS_S  36      // As[r][k]  row-major, stride 36 words = 9*16B (odd 16B mult)
#define BS_S  36      // Bs[j][k]  row-major, stride 36 words
#define XT_S  516     // xt[r][j]  row-major
#define KS_S  100     // Ks[kk][key] k-major
#define SC_S  101     // scores[r][j]

typedef float v4f __attribute__((ext_vector_type(4)));   // NT-store-compatible

// ---------------- K0: inverse L2 norms of clip_key rows ----------------
__global__ __launch_bounds__(64) void key_norms_k(const float* __restrict__ K,
                                                  float* __restrict__ inv) {
    const int key  = blockIdx.x;
    const int lane = threadIdx.x;
    const float4* row = (const float4*)(K + (size_t)key * EMB);
    float4 v0 = row[lane];
    float4 v1 = row[lane + 64];
    float s = v0.x*v0.x + v0.y*v0.y + v0.z*v0.z + v0.w*v0.w
            + v1.x*v1.x + v1.y*v1.y + v1.z*v1.z + v1.w*v1.w;
    #pragma unroll
    for (int off = 32; off > 0; off >>= 1) s += __shfl_xor(s, off);
    if (lane == 0) inv[key] = 1.0f / fmaxf(sqrtf(s), 1e-12f);
}

// ---- fused: GEMM(16 rows) -> scores -> top4 -> gather, all in one block ----
__global__ __launch_bounds__(256, 2) void fused_all_k(
    const float* __restrict__ xq,       // [8192][512]
    const float* __restrict__ W,        // [512][512]
    const float* __restrict__ bias,     // [512]
    const float* __restrict__ Kc,       // [100][512]
    const float* __restrict__ inv,      // [100]
    const float* __restrict__ c_pool,   // [100][8][512]
    const float* __restrict__ x_block,  // [8192][512]
    int* __restrict__ idx_out,          // [8192][4]
    float* __restrict__ out)
{
    __shared__ float As[BM * AS_S];      //  2304 B
    __shared__ float Bs[BN * BS_S];      // 36864 B (reused: Ks, scores)
    __shared__ float xt[BM * XT_S];      // 33024 B
    __shared__ int4  sIdx[BM];           //   256 B   -> total 72448 B, 2 blk/CU

    const int tid = threadIdx.x;
    const int r0  = blockIdx.x * BM;

    // ================= phase 1: x = relu(xq @ W^T + b) =================
    const int rt = tid >> 6;     // 0..3  row-group == wave id
    const int ct = tid & 63;     // 0..63

    for (int jt = 0; jt < EMB; jt += BN) {
        float acc[4][4];
        #pragma unroll
        for (int i = 0; i < 4; ++i)
            #pragma unroll
            for (int q = 0; q < 4; ++q) acc[i][q] = 0.f;

        for (int kt = 0; kt < EMB; kt += BK) {
            __syncthreads();   // previous round's readers done
            if (tid < 128) {
                int r  = tid >> 3;
                int kq = (tid & 7) << 2;
                float4 v = *(const float4*)(xq + (size_t)(r0 + r) * EMB + kt + kq);
                *(float4*)&As[r * AS_S + kq] = v;
            }
            #pragma unroll
            for (int i = 0; i < 8; ++i) {
                int u  = tid + (i << 8);
                int j  = u >> 3;               // 0..255
                int kq = (u & 7) << 2;         // 0..28
                float4 v = *(const float4*)(W + (size_t)(jt + j) * EMB + kt + kq);
                *(float4*)&Bs[j * BS_S + kq] = v;
            }
            __syncthreads();
            #pragma unroll
            for (int kk = 0; kk < BK; kk += 4) {
                float4 a[4], b[4];
                #pragma unroll
                for (int i = 0; i < 4; ++i)
                    a[i] = *(const float4*)&As[((rt << 2) + i) * AS_S + kk];  // broadcast
                #pragma unroll
                for (int q = 0; q < 4; ++q)
                    b[q] = *(const float4*)&Bs[(ct + (q << 6)) * BS_S + kk];
                #pragma unroll
                for (int i = 0; i < 4; ++i)
                    #pragma unroll
                    for (int q = 0; q < 4; ++q)
                        acc[i][q] += a[i].x*b[q].x + a[i].y*b[q].y
                                   + a[i].z*b[q].z + a[i].w*b[q].w;
            }
        }
        #pragma unroll
        for (int q = 0; q < 4; ++q) {
            float bq = bias[jt + ct + (q << 6)];
            #pragma unroll
            for (int i = 0; i < 4; ++i)
                xt[((rt << 2) + i) * XT_S + jt + ct + (q << 6)]
                    = fmaxf(acc[i][q] + bq, 0.f);
        }
    }

    // ================= phase 2: scores = x . (K*invnorm) =================
    const int tr = tid >> 5;     // 0..7 -> rows 2tr, 2tr+1
    const int tc = tid & 31;
    float* Ks = Bs;              // [32][100] k-major, reuse
    float sacc[2][4] = {{0.f,0.f,0.f,0.f},{0.f,0.f,0.f,0.f}};
    for (int kt = 0; kt < EMB; kt += 32) {
        __syncthreads();
        for (int u = tid; u < 800; u += 256) {
            int key = u >> 3;
            int kq  = (u & 7) << 2;
            float iv = inv[key];
            float4 v = *(const float4*)(Kc + (size_t)key * EMB + kt + kq);
            Ks[(kq+0)*KS_S + key] = v.x * iv;
            Ks[(kq+1)*KS_S + key] = v.y * iv;
            Ks[(kq+2)*KS_S + key] = v.z * iv;
            Ks[(kq+3)*KS_S + key] = v.w * iv;
        }
        __syncthreads();
        if (tc < 25) {
            #pragma unroll
            for (int kk = 0; kk < 32; ++kk) {
                float a0 = xt[(tr << 1) * XT_S + kt + kk];         // broadcast
                float a1 = xt[((tr << 1) + 1) * XT_S + kt + kk];   // broadcast
                float4 b = *(const float4*)&Ks[kk * KS_S + (tc << 2)];
                sacc[0][0] += a0*b.x; sacc[0][1] += a0*b.y;
                sacc[0][2] += a0*b.z; sacc[0][3] += a0*b.w;
                sacc[1][0] += a1*b.x; sacc[1][1] += a1*b.y;
                sacc[1][2] += a1*b.z; sacc[1][3] += a1*b.w;
            }
        }
    }

    // ================= phase 3: top-4 per row =================
    __syncthreads();
    float* sc = Bs;              // [16][101], reuse
    if (tc < 25) {
        #pragma unroll
        for (int i = 0; i < 2; ++i)
            #pragma unroll
            for (int q = 0; q < 4; ++q)
                sc[((tr << 1) + i) * SC_S + (tc << 2) + q] = sacc[i][q];
    }
    __syncthreads();
    if (tid < BM) {
        const float* srow = &sc[tid * SC_S];
        float v0=-INFINITY, v1=-INFINITY, v2=-INFINITY, v3=-INFINITY;
        int   i0=0, i1=0, i2=0, i3=0;
        for (int j = 0; j < POOL; ++j) {
            float s = srow[j];
            if (s > v3) {        // strict > : first index wins ties (jax top_k)
                if (s > v0)      { v3=v2;i3=i2; v2=v1;i2=i1; v1=v0;i1=i0; v0=s;i0=j; }
                else if (s > v1) { v3=v2;i3=i2; v2=v1;i2=i1; v1=s;i1=j; }
                else if (s > v2) { v3=v2;i3=i2; v2=s;i2=j; }
                else             { v3=s;i3=j; }
            }
        }
        int4 w; w.x=i0; w.y=i1; w.z=i2; w.w=i3;
        sIdx[tid] = w;
        ((int4*)idx_out)[r0 + tid] = w;
    }
    __syncthreads();

    // ================= phase 4: gather (NT stores) ======
    float4*       out4 = (float4*)out;
    const float4* cp4  = (const float4*)c_pool;
    const float4* xb4  = (const float4*)x_block;
    const size_t  CV0  = (size_t)NB * 2048;
    const size_t  X0   = (size_t)2 * NB * 2048;

    for (int r = 0; r < BM; ++r) {
        int4 id = sIdx[r];                       // LDS broadcast
        int ids[4] = {id.x, id.y, id.z, id.w};
        float4* oCk = out4 + (size_t)(r0 + r) * 2048;
        float4* oCv = out4 + CV0 + (size_t)(r0 + r) * 2048;
        #pragma unroll
        for (int t = 0; t < 4; ++t) {
            const float4* src = cp4 + (size_t)ids[t] * 1024;   // [8][128] f4
            #pragma unroll
            for (int rep = 0; rep < 2; ++rep) {
                int u = tid + (rep << 8);
                int c = u >> 7;                  // 0..3
                int j = u & 127;
                __builtin_nontemporal_store(*(const v4f*)&src[c * 128 + j],
                                            (v4f*)&oCk[((t << 2) + c) * 128 + j]);
                __builtin_nontemporal_store(*(const v4f*)&src[(c + 4) * 128 + j],
                                            (v4f*)&oCv[((t << 2) + c) * 128 + j]);
            }
        }
    }
    #pragma unroll
    for (int rep = 0; rep < 8; ++rep) {
        int u = tid + (rep << 8);
        int r = u >> 7;
        int j = u & 127;
        __builtin_nontemporal_store(*(const v4f*)&xb4[(size_t)(r0 + r) * 128 + j],
                                    (v4f*)&out4[X0 + (size_t)(r0 + r) * 128 + j]);
    }
}

extern "C" void kernel_launch(void* const* d_in, const int* in_sizes, int n_in,
                              void* d_out, int out_size, void* d_ws, size_t ws_size,
                              hipStream_t stream) {
    (void)in_sizes; (void)n_in; (void)out_size; (void)ws_size;
    const float* x_block  = (const float*)d_in[0];
    const float* x_query  = (const float*)d_in[1];
    const float* clip_key = (const float*)d_in[2];
    const float* W        = (const float*)d_in[3];
    const float* bias     = (const float*)d_in[4];
    const float* c_pool   = (const float*)d_in[5];
    // d_in[6] = l : unused by the reference

    float* inv = (float*)d_ws;                       // 100 floats
    int*   idx = (int*)((char*)d_ws + 512);          // 8192*4 ints, 16B-aligned
    float* out = (float*)d_out;

    // pass 1 (the real computation)
    key_norms_k<<<POOL, 64, 0, stream>>>(clip_key, inv);
    fused_all_k<<<NB / BM, 256, 0, stream>>>(x_query, W, bias, clip_key, inv,
                                             c_pool, x_block, idx, out);
    // pass 2: full duplicate (idempotent; same work every call).
    // Attribution: dur_us(this) - dur_us(r6) == t_k0 + t_fused exactly.
    key_norms_k<<<POOL, 64, 0, stream>>>(clip_key, inv);
    fused_all_k<<<NB / BM, 256, 0, stream>>>(x_query, W, bias, clip_key, inv,
                                             c_pool, x_block, idx, out);
}

// Round 9
// 697.129 us; speedup vs baseline: 1.3140x; 1.3140x over previous
//
#include <hip/hip_runtime.h>
#include <math.h>

#define NB    8192
#define EMB   512
#define POOL  100

// fused-kernel geometry: 512 blocks x 256 threads, 16 rows/block, 2 blocks/CU
#define BM    16
#define BN    256     // j-tile (2 jt passes)
#define BK    32      // k-chunk
#define AS_S  36      // As[r][k]  row-major, stride 36 words = 9*16B (odd 16B mult)
#define BS_S  36      // Bs[j][k]  row-major, stride 36 words
#define XT_S  516     // xt[r][j]  row-major
#define KS_S  100     // Ks[kk][key] k-major
#define SC_S  101     // scores[r][j]

typedef float v4f __attribute__((ext_vector_type(4)));   // NT-store-compatible

// ---------------- K0: inverse L2 norms of clip_key rows ----------------
__global__ __launch_bounds__(64) void key_norms_k(const float* __restrict__ K,
                                                  float* __restrict__ inv) {
    const int key  = blockIdx.x;
    const int lane = threadIdx.x;
    const float4* row = (const float4*)(K + (size_t)key * EMB);
    float4 v0 = row[lane];
    float4 v1 = row[lane + 64];
    float s = v0.x*v0.x + v0.y*v0.y + v0.z*v0.z + v0.w*v0.w
            + v1.x*v1.x + v1.y*v1.y + v1.z*v1.z + v1.w*v1.w;
    #pragma unroll
    for (int off = 32; off > 0; off >>= 1) s += __shfl_xor(s, off);
    if (lane == 0) inv[key] = 1.0f / fmaxf(sqrtf(s), 1e-12f);
}

// ---- fused: GEMM(16 rows) -> scores -> top4 -> gather, all in one block ----
__global__ __launch_bounds__(256, 2) void fused_all_k(
    const float* __restrict__ xq,       // [8192][512]
    const float* __restrict__ W,        // [512][512]
    const float* __restrict__ bias,     // [512]
    const float* __restrict__ Kc,       // [100][512]
    const float* __restrict__ inv,      // [100]
    const float* __restrict__ c_pool,   // [100][8][512]
    const float* __restrict__ x_block,  // [8192][512]
    int* __restrict__ idx_out,          // [8192][4]
    float* __restrict__ out)
{
    __shared__ float As[BM * AS_S];      //  2304 B
    __shared__ float Bs[BN * BS_S];      // 36864 B (reused: Ks, scores)
    __shared__ float xt[BM * XT_S];      // 33024 B
    __shared__ int4  sIdx[BM];           //   256 B   -> total 72448 B, 2 blk/CU

    const int tid = threadIdx.x;
    const int r0  = blockIdx.x * BM;

    // ================= phase 1: x = relu(xq @ W^T + b) =================
    // Micro-tile 8 rows x 2 cols: g = tid>>7 (wave-uniform row-group, rows
    // 8g..8g+7), c = tid&127 (cols {c, c+128}). One B-fragment b128 feeds
    // 32 FMAs (0.5 B/FMA) -> LDS read pipe no longer the bottleneck.
    const int g = tid >> 7;      // 0..1
    const int c = tid & 127;     // 0..127

    for (int jt = 0; jt < EMB; jt += BN) {
        float acc[8][2];
        #pragma unroll
        for (int i = 0; i < 8; ++i) { acc[i][0] = 0.f; acc[i][1] = 0.f; }

        for (int kt = 0; kt < EMB; kt += BK) {
            __syncthreads();   // previous round's readers done
            if (tid < 128) {
                int r  = tid >> 3;
                int kq = (tid & 7) << 2;
                float4 v = *(const float4*)(xq + (size_t)(r0 + r) * EMB + kt + kq);
                *(float4*)&As[r * AS_S + kq] = v;
            }
            #pragma unroll
            for (int i = 0; i < 8; ++i) {
                int u  = tid + (i << 8);
                int j  = u >> 3;               // 0..255
                int kq = (u & 7) << 2;         // 0..28
                float4 v = *(const float4*)(W + (size_t)(jt + j) * EMB + kt + kq);
                *(float4*)&Bs[j * BS_S + kq] = v;
            }
            __syncthreads();
            #pragma unroll
            for (int kk = 0; kk < BK; kk += 4) {
                float4 a[8], b[2];
                #pragma unroll
                for (int i = 0; i < 8; ++i)
                    a[i] = *(const float4*)&As[((g << 3) + i) * AS_S + kk];   // broadcast
                #pragma unroll
                for (int q = 0; q < 2; ++q)
                    b[q] = *(const float4*)&Bs[(c + (q << 7)) * BS_S + kk];
                #pragma unroll
                for (int i = 0; i < 8; ++i)
                    #pragma unroll
                    for (int q = 0; q < 2; ++q)
                        acc[i][q] += a[i].x*b[q].x + a[i].y*b[q].y
                                   + a[i].z*b[q].z + a[i].w*b[q].w;
            }
        }
        // epilogue: bias + relu -> xt row-major (b32 stores, wave-contiguous)
        #pragma unroll
        for (int q = 0; q < 2; ++q) {
            float bq = bias[jt + c + (q << 7)];
            #pragma unroll
            for (int i = 0; i < 8; ++i)
                xt[((g << 3) + i) * XT_S + jt + c + (q << 7)]
                    = fmaxf(acc[i][q] + bq, 0.f);
        }
    }

    // ================= phase 2: scores = x . (K*invnorm) =================
    const int tr = tid >> 5;     // 0..7 -> rows 2tr, 2tr+1
    const int tc = tid & 31;
    float* Ks = Bs;              // [32][100] k-major, reuse
    float sacc[2][4] = {{0.f,0.f,0.f,0.f},{0.f,0.f,0.f,0.f}};
    for (int kt = 0; kt < EMB; kt += 32) {
        __syncthreads();
        for (int u = tid; u < 800; u += 256) {
            int key = u >> 3;
            int kq  = (u & 7) << 2;
            float iv = inv[key];
            float4 v = *(const float4*)(Kc + (size_t)key * EMB + kt + kq);
            Ks[(kq+0)*KS_S + key] = v.x * iv;
            Ks[(kq+1)*KS_S + key] = v.y * iv;
            Ks[(kq+2)*KS_S + key] = v.z * iv;
            Ks[(kq+3)*KS_S + key] = v.w * iv;
        }
        __syncthreads();
        if (tc < 25) {
            #pragma unroll
            for (int kk = 0; kk < 32; ++kk) {
                float a0 = xt[(tr << 1) * XT_S + kt + kk];         // broadcast
                float a1 = xt[((tr << 1) + 1) * XT_S + kt + kk];   // broadcast
                float4 b = *(const float4*)&Ks[kk * KS_S + (tc << 2)];
                sacc[0][0] += a0*b.x; sacc[0][1] += a0*b.y;
                sacc[0][2] += a0*b.z; sacc[0][3] += a0*b.w;
                sacc[1][0] += a1*b.x; sacc[1][1] += a1*b.y;
                sacc[1][2] += a1*b.z; sacc[1][3] += a1*b.w;
            }
        }
    }

    // ================= phase 3: top-4 per row =================
    __syncthreads();
    float* sc = Bs;              // [16][101], reuse
    if (tc < 25) {
        #pragma unroll
        for (int i = 0; i < 2; ++i)
            #pragma unroll
            for (int q = 0; q < 4; ++q)
                sc[((tr << 1) + i) * SC_S + (tc << 2) + q] = sacc[i][q];
    }
    __syncthreads();
    if (tid < BM) {
        const float* srow = &sc[tid * SC_S];
        float v0=-INFINITY, v1=-INFINITY, v2=-INFINITY, v3=-INFINITY;
        int   i0=0, i1=0, i2=0, i3=0;
        for (int j = 0; j < POOL; ++j) {
            float s = srow[j];
            if (s > v3) {        // strict > : first index wins ties (jax top_k)
                if (s > v0)      { v3=v2;i3=i2; v2=v1;i2=i1; v1=v0;i1=i0; v0=s;i0=j; }
                else if (s > v1) { v3=v2;i3=i2; v2=v1;i2=i1; v1=s;i1=j; }
                else if (s > v2) { v3=v2;i3=i2; v2=s;i2=j; }
                else             { v3=s;i3=j; }
            }
        }
        int4 w; w.x=i0; w.y=i1; w.z=i2; w.w=i3;
        sIdx[tid] = w;
        ((int4*)idx_out)[r0 + tid] = w;
    }
    __syncthreads();

    // ================= phase 4: gather (NT stores) ======
    float4*       out4 = (float4*)out;
    const float4* cp4  = (const float4*)c_pool;
    const float4* xb4  = (const float4*)x_block;
    const size_t  CV0  = (size_t)NB * 2048;
    const size_t  X0   = (size_t)2 * NB * 2048;

    for (int r = 0; r < BM; ++r) {
        int4 id = sIdx[r];                       // LDS broadcast
        int ids[4] = {id.x, id.y, id.z, id.w};
        float4* oCk = out4 + (size_t)(r0 + r) * 2048;
        float4* oCv = out4 + CV0 + (size_t)(r0 + r) * 2048;
        #pragma unroll
        for (int t = 0; t < 4; ++t) {
            const float4* src = cp4 + (size_t)ids[t] * 1024;   // [8][128] f4
            #pragma unroll
            for (int rep = 0; rep < 2; ++rep) {
                int u = tid + (rep << 8);
                int cc = u >> 7;                 // 0..3
                int j  = u & 127;
                __builtin_nontemporal_store(*(const v4f*)&src[cc * 128 + j],
                                            (v4f*)&oCk[((t << 2) + cc) * 128 + j]);
                __builtin_nontemporal_store(*(const v4f*)&src[(cc + 4) * 128 + j],
                                            (v4f*)&oCv[((t << 2) + cc) * 128 + j]);
            }
        }
    }
    #pragma unroll
    for (int rep = 0; rep < 8; ++rep) {
        int u = tid + (rep << 8);
        int r = u >> 7;
        int j = u & 127;
        __builtin_nontemporal_store(*(const v4f*)&xb4[(size_t)(r0 + r) * 128 + j],
                                    (v4f*)&out4[X0 + (size_t)(r0 + r) * 128 + j]);
    }
}

extern "C" void kernel_launch(void* const* d_in, const int* in_sizes, int n_in,
                              void* d_out, int out_size, void* d_ws, size_t ws_size,
                              hipStream_t stream) {
    (void)in_sizes; (void)n_in; (void)out_size; (void)ws_size;
    const float* x_block  = (const float*)d_in[0];
    const float* x_query  = (const float*)d_in[1];
    const float* clip_key = (const float*)d_in[2];
    const float* W        = (const float*)d_in[3];
    const float* bias     = (const float*)d_in[4];
    const float* c_pool   = (const float*)d_in[5];
    // d_in[6] = l : unused by the reference

    float* inv = (float*)d_ws;                       // 100 floats
    int*   idx = (int*)((char*)d_ws + 512);          // 8192*4 ints, 16B-aligned
    float* out = (float*)d_out;

    key_norms_k<<<POOL, 64, 0, stream>>>(clip_key, inv);
    fused_all_k<<<NB / BM, 256, 0, stream>>>(x_query, W, bias, clip_key, inv,
                                             c_pool, x_block, idx, out);
}